// Round 9
// baseline (13410.019 us; speedup 1.0000x reference)
//
#include <hip/hip_runtime.h>
#include <hip/hip_bf16.h>

// ---------------- problem constants ----------------
#define B_ 1024
#define T_ 365
#define D_ 24
#define H_ 128
#define NG 32            // batch groups
#define NS 8             // hidden slices (blocks per group)
#define GB 32            // batch rows per group

// per-slice weight arena: 102 tiles x 512 ushorts ([khi4][nlo16][e8] frag layout)
// tile bases: WIH1 0(3), WIH2 3(3), WHH1 6(12), WHH2 18(12),
//             WIH3 30(24), WHH3 54(12), WIH4 66(24), WHH4 90(12)
#define SLICE_EL 52224
#define ARENA_EL (8 * SLICE_EL)

typedef __attribute__((ext_vector_type(8))) short bf16x8;
typedef __attribute__((ext_vector_type(4))) float f32x4;

__device__ __align__(16) unsigned short g_arena[ARENA_EL];
__device__ __align__(16) unsigned g_mb[4][NG][2048];  // [cell][group][kg16][row32][e4(pairs)]
__device__ unsigned g_flags[NG][4];

#define MFMA(a, b, c) __builtin_amdgcn_mfma_f32_16x16x32_bf16((a), (b), (c), 0, 0, 0)

__device__ __forceinline__ bf16x8 ldw(const unsigned short* p) {
  return *(const bf16x8*)p;
}
__device__ __forceinline__ unsigned short f2b(float f) {
  union { __hip_bfloat16 h; unsigned short u; } cv;
  cv.h = __float2bfloat16(f);   // RNE
  return cv.u;
}
__device__ __forceinline__ float b2f(unsigned short u) {
  union { float f; unsigned int u32; } cv;
  cv.u32 = ((unsigned int)u) << 16;
  return cv.f;
}
__device__ __forceinline__ float sigmoidf_(float x) { return 1.f / (1.f + __expf(-x)); }
__device__ __forceinline__ float tanhf_(float x) {
  float e = __expf(2.f * x);
  return 1.f - 2.f / (e + 1.f);
}

// ---------------- prologue: fp32 -> per-slice fragment-major bf16 arena ----------------
__global__ void prep_weights(const float* wih1, const float* wih2,
                             const float* wih3, const float* wih4,
                             const float* whh1, const float* whh2,
                             const float* whh3, const float* whh4) {
  int i = blockIdx.x * blockDim.x + threadIdx.x;
  if (i < NG * 4) ((unsigned*)g_flags)[i] = 0;   // zero sync flags each launch
  if (i >= ARENA_EL) return;
  int s = i / SLICE_EL, r = i % SLICE_EL;
  int tile = r >> 9, wi = r & 511;
  int khi = wi >> 7, nlo = (wi >> 3) & 15, e = wi & 7;
  float v = 0.f;
  if (tile < 3) {
    int row = tile * 128 + s * 16 + nlo, k = khi * 8 + e;
    if (k < 24) v = wih1[row * 24 + k];
  } else if (tile < 6) {
    int row = (tile - 3) * 128 + s * 16 + nlo, k = khi * 8 + e;
    if (k < 25) v = wih2[row * 25 + k];            // k=24 -> lai weight
  } else if (tile < 18) {
    int tt = tile - 6; int row = (tt >> 2) * 128 + s * 16 + nlo;
    v = whh1[row * 128 + (tt & 3) * 32 + khi * 8 + e];
  } else if (tile < 30) {
    int tt = tile - 18; int row = (tt >> 2) * 128 + s * 16 + nlo;
    v = whh2[row * 128 + (tt & 3) * 32 + khi * 8 + e];
  } else if (tile < 54) {
    int tt = tile - 30; int row = (tt >> 3) * 128 + s * 16 + nlo;
    v = wih3[row * 256 + (tt & 7) * 32 + khi * 8 + e];
  } else if (tile < 66) {
    int tt = tile - 54; int row = (tt >> 2) * 128 + s * 16 + nlo;
    v = whh3[row * 128 + (tt & 3) * 32 + khi * 8 + e];
  } else if (tile < 90) {
    int tt = tile - 66; int row = (tt >> 3) * 128 + s * 16 + nlo;
    v = wih4[row * 256 + (tt & 7) * 32 + khi * 8 + e];
  } else {
    int tt = tile - 90; int row = (tt >> 2) * 128 + s * 16 + nlo;
    v = whh4[row * 128 + (tt & 3) * 32 + khi * 8 + e];
  }
  g_arena[i] = f2b(v);
}

// ---------------- params ----------------
struct P {
  const float* x;
  const float* bih[4];
  const float* bhh[4];
  const float* wfc[4];
  const float* bfc[4];
  float* out;      // [B][T][9]
  float* hf[4];    // [B][128]
  float* hT[4];    // [B][T][128]
};

// group sync (round-2-proven recipe; __syncthreads drains all waves' vmem first)
__device__ __forceinline__ void gsync(int g, int st, unsigned target) {
  __syncthreads();
  if (threadIdx.x == 0) {
    __builtin_amdgcn_fence(__ATOMIC_RELEASE, "agent");
    __hip_atomic_fetch_add(&g_flags[g][st], 1u, __ATOMIC_RELAXED, __HIP_MEMORY_SCOPE_AGENT);
    unsigned spins = 0;
    while (__hip_atomic_load(&g_flags[g][st], __ATOMIC_RELAXED, __HIP_MEMORY_SCOPE_AGENT) < target) {
      if (++spins > (1u << 24)) break;   // bounded bail-out (fails loudly, never hangs)
    }
    __builtin_amdgcn_fence(__ATOMIC_ACQUIRE, "agent");
  }
  __syncthreads();
}

// dynamic LDS layout (bytes)
#define L_WSL  0u         // 102 KB weight slice
#define L_HBUF 104448u    // 4 cells x [16kg][32row][8e] ushort = 32768
#define L_PSUM 137216u    // [4 slot][2 mt][16 m][16 n] f32 = 8192
#define L_XA   145408u    // [4kg][32][8] ushort = 2048
#define L_FCW  147456u    // [9][128] f32 = 4608
#define SMEMB  152064u

__global__ __launch_bounds__(256, 1) void gru_main(P p) {
  extern __shared__ __align__(16) unsigned char smem[];
  unsigned short* wsl = (unsigned short*)(smem + L_WSL);
  unsigned short* hbuf = (unsigned short*)(smem + L_HBUF);
  float* psum = (float*)(smem + L_PSUM);
  unsigned short* xa = (unsigned short*)(smem + L_XA);
  float (*fcw)[H_] = (float (*)[H_])(smem + L_FCW);

  const int tid = threadIdx.x;
  const int lane = tid & 63;
  const int w = tid >> 6;            // wave role: 0=R 1=Z 2=In 3=Hn
  const int nlo = lane & 15, khi = lane >> 4;
  const int g = blockIdx.x >> 3, s = blockIdx.x & 7;
  const int b0 = g * GB;
  const int wkoff = khi * 128 + nlo * 8;   // weight-frag offset (ushorts)
  const int hkoff = khi * 256 + nlo * 8;   // h/x-frag offset
  const int row = tid >> 3, cp = tid & 7;  // nonlin/FC ownership: 2 cols per thread
  const int col0 = s * 16 + cp * 2;
  const int mbw = (col0 >> 3) * 128 + row * 4 + ((col0 & 7) >> 1);  // word index

  // ---- prologue ----
  { const uint4* srcw = (const uint4*)(g_arena + s * SLICE_EL);
    uint4* dstw = (uint4*)wsl;
    for (int i = tid; i < SLICE_EL / 8; i += 256) dstw[i] = srcw[i]; }
  for (int i = tid; i < 8192; i += 256) ((unsigned*)hbuf)[i] = 0;
  for (int i = tid; i < 1024; i += 256) {       // xa for t=0 (lai=0, pad=0)
    int kg = i >> 8, rem = i & 255, r2 = rem >> 3, e = i & 7;
    int c = kg * 8 + e;
    unsigned short vv = 0;
    if (c < 24) vv = f2b(p.x[(size_t)(b0 + r2) * (T_ * D_) + c]);
    xa[i] = vv;
  }
  for (int i = tid; i < 9 * H_; i += 256) {
    int rw = i >> 7, k = i & 127;
    const float* srcf; int lr;
    if (rw == 0)      { srcf = p.wfc[0]; lr = 0; }
    else if (rw < 4)  { srcf = p.wfc[1]; lr = rw - 1; }
    else if (rw < 7)  { srcf = p.wfc[2]; lr = rw - 4; }
    else              { srcf = p.wfc[3]; lr = rw - 7; }
    fcw[rw][k] = srcf[lr * H_ + k];
  }

  float bR[4][2], bZ[4][2], bI[4][2], bHn[4][2], hreg[4][2];
#pragma unroll
  for (int c = 0; c < 4; ++c)
#pragma unroll
    for (int j = 0; j < 2; ++j) {
      int cc = col0 + j;
      bR[c][j]  = p.bih[c][cc] + p.bhh[c][cc];
      bZ[c][j]  = p.bih[c][H_ + cc] + p.bhh[c][H_ + cc];
      bI[c][j]  = p.bih[c][2 * H_ + cc];
      bHn[c][j] = p.bhh[c][2 * H_ + cc];
      hreg[c][j] = 0.f;
    }
  const float bfc7 = p.bfc[3][0];
  const float bfc8 = p.bfc[3][1];
  int fc_c = 0; float fcb = 0.f;
  if (s == 0)      { fc_c = 0; fcb = p.bfc[0][0]; }
  else if (s < 4)  { fc_c = 1; fcb = p.bfc[1][s - 1]; }
  else if (s < 7)  { fc_c = 2; fcb = p.bfc[2][s - 4]; }

  float* hTp[4];
#pragma unroll
  for (int c = 0; c < 4; ++c)
    hTp[c] = p.hT[c] + (size_t)(b0 + row) * (T_ * H_) + col0;
  float* outp = p.out + (size_t)(b0 + row) * (T_ * 9);

  const f32x4 zf = {0.f, 0.f, 0.f, 0.f};

#define WF(tt)        ldw(wsl + (tt) * 512 + wkoff)
#define HF(c, kc, mt) ldw(hbuf + (c) * 4096 + (kc) * 1024 + (mt) * 128 + hkoff)
#define XF(mt)        ldw(xa + (mt) * 128 + hkoff)
#define PWR(slot, mt, v) do { \
  float* pp_ = psum + (slot) * 512 + (mt) * 256 + khi * 64 + nlo; \
  pp_[0] = (v)[0]; pp_[16] = (v)[1]; pp_[32] = (v)[2]; pp_[48] = (v)[3]; \
} while (0)

#define STAGE_A(C, TWX, THX) do { \
  if (w < 2) { \
    _Pragma("unroll") \
    for (int mt = 0; mt < 2; ++mt) { \
      f32x4 acc = MFMA(XF(mt), WF((TWX) + w), zf); \
      _Pragma("unroll") \
      for (int kc = 0; kc < 4; ++kc) acc = MFMA(HF(C, kc, mt), WF((THX) + w * 4 + kc), acc); \
      PWR(w, mt, acc); \
    } \
  } else if (w == 2) { \
    _Pragma("unroll") \
    for (int mt = 0; mt < 2; ++mt) { f32x4 acc = MFMA(XF(mt), WF((TWX) + 2), zf); PWR(2, mt, acc); } \
  } else { \
    _Pragma("unroll") \
    for (int mt = 0; mt < 2; ++mt) { \
      f32x4 acc = zf; \
      _Pragma("unroll") \
      for (int kc = 0; kc < 4; ++kc) acc = MFMA(HF(C, kc, mt), WF((THX) + 8 + kc), acc); \
      PWR(3, mt, acc); \
    } \
  } \
} while (0)

#define STAGE_BC(CA, CB, CH, TWX, THX) do { \
  if (w < 2) { \
    _Pragma("unroll") \
    for (int mt = 0; mt < 2; ++mt) { \
      f32x4 acc = zf; \
      _Pragma("unroll") \
      for (int kc = 0; kc < 4; ++kc) acc = MFMA(HF(CA, kc, mt), WF((TWX) + w * 8 + kc), acc); \
      _Pragma("unroll") \
      for (int kc = 0; kc < 4; ++kc) acc = MFMA(HF(CB, kc, mt), WF((TWX) + w * 8 + 4 + kc), acc); \
      _Pragma("unroll") \
      for (int kc = 0; kc < 4; ++kc) acc = MFMA(HF(CH, kc, mt), WF((THX) + w * 4 + kc), acc); \
      PWR(w, mt, acc); \
    } \
  } else if (w == 2) { \
    _Pragma("unroll") \
    for (int mt = 0; mt < 2; ++mt) { \
      f32x4 acc = zf; \
      _Pragma("unroll") \
      for (int kc = 0; kc < 4; ++kc) acc = MFMA(HF(CA, kc, mt), WF((TWX) + 16 + kc), acc); \
      _Pragma("unroll") \
      for (int kc = 0; kc < 4; ++kc) acc = MFMA(HF(CB, kc, mt), WF((TWX) + 16 + 4 + kc), acc); \
      PWR(2, mt, acc); \
    } \
  } else { \
    _Pragma("unroll") \
    for (int mt = 0; mt < 2; ++mt) { \
      f32x4 acc = zf; \
      _Pragma("unroll") \
      for (int kc = 0; kc < 4; ++kc) acc = MFMA(HF(CH, kc, mt), WF((THX) + 8 + kc), acc); \
      PWR(3, mt, acc); \
    } \
  } \
} while (0)

#define FIN(C) do { \
  const float* pb_ = psum + (row >> 4) * 256 + (row & 15) * 16 + cp * 2; \
  float R0 = pb_[0],    Ra = pb_[1]; \
  float Z0 = pb_[512],  Za = pb_[513]; \
  float I0 = pb_[1024], Ia = pb_[1025]; \
  float G0 = pb_[1536], Ga = pb_[1537]; \
  float r0 = sigmoidf_(R0 + bR[C][0]), r1 = sigmoidf_(Ra + bR[C][1]); \
  float z0 = sigmoidf_(Z0 + bZ[C][0]), z1 = sigmoidf_(Za + bZ[C][1]); \
  float n0 = tanhf_(I0 + bI[C][0] + r0 * (G0 + bHn[C][0])); \
  float n1 = tanhf_(Ia + bI[C][1] + r1 * (Ga + bHn[C][1])); \
  float h0 = (1.f - z0) * n0 + z0 * hreg[C][0]; \
  float h1 = (1.f - z1) * n1 + z1 * hreg[C][1]; \
  hreg[C][0] = h0; hreg[C][1] = h1; \
  unsigned pk_ = (unsigned)f2b(h0) | ((unsigned)f2b(h1) << 16); \
  __hip_atomic_store(&g_mb[C][g][0] + mbw, pk_, \
                     __ATOMIC_RELAXED, __HIP_MEMORY_SCOPE_AGENT); \
  union { float f[2]; unsigned long long u; } cv_; \
  cv_.f[0] = h0; cv_.f[1] = h1; \
  __builtin_nontemporal_store(cv_.u, (unsigned long long*)hTp[C]); \
  hTp[C] += H_; \
} while (0)

#define COPYMB(C) do { \
  const uint4* sm_ = (const uint4*)&g_mb[C][g][0]; \
  uint4* dm_ = (uint4*)(hbuf + (C) * 4096); \
  dm_[tid] = sm_[tid]; dm_[tid + 256] = sm_[tid + 256]; \
} while (0)

  __syncthreads();

  for (int t = 0; t < T_; ++t) {
    // ===== stage A: cell1 =====
    STAGE_A(0, 0, 6);
    __syncthreads();
    FIN(0);
    __syncthreads();
    // ===== stage A: cell2 (xa col24 = lai) =====
    STAGE_A(1, 3, 18);
    __syncthreads();
    FIN(1);
    gsync(g, 0, 8u * (t + 1));

    // ===== stage B: cell3 =====
    COPYMB(0); COPYMB(1);       // h1,h2 new -> hbuf
    __syncthreads();
    STAGE_BC(0, 1, 2, 30, 54);
    __syncthreads();
    FIN(2);
    gsync(g, 1, 8u * (t + 1));

    // ===== stage C: cell4 =====
    COPYMB(2);                  // h3 new -> hbuf
    __syncthreads();
    STAGE_BC(0, 2, 3, 66, 90);
    __syncthreads();
    FIN(3);
    gsync(g, 2, 8u * (t + 1));

    // ===== FC phase =====
    COPYMB(3);                  // h4 new -> hbuf
    if (t + 1 < T_) {           // stage x_{t+1}
      for (int i = tid; i < GB * D_; i += 256) {
        int r2 = i / D_, cc = i % D_;
        xa[(cc >> 3) * 256 + r2 * 8 + (cc & 7)] =
            f2b(p.x[(size_t)(b0 + r2) * (T_ * D_) + (size_t)(t + 1) * D_ + cc]);
      }
    }
    __syncthreads();
    {
      // lai (all slices, redundant): o4[:,0] = h4 . wfc4[0] + b
      float hx[16];
      const unsigned short* hp = hbuf + 3 * 4096 + (cp * 2) * 256 + row * 8;
      bf16x8 v0 = ldw(hp), v1 = ldw(hp + 256);
#pragma unroll
      for (int e = 0; e < 8; ++e) {
        hx[e] = b2f((unsigned short)v0[e]);
        hx[8 + e] = b2f((unsigned short)v1[e]);
      }
      float acc = 0.f;
#pragma unroll
      for (int j = 0; j < 16; ++j) acc += hx[j] * fcw[7][cp * 16 + j];
      acc += __shfl_xor(acc, 1); acc += __shfl_xor(acc, 2); acc += __shfl_xor(acc, 4);
      float laiv = acc + bfc7;
      if (cp == 0) {
        xa[3 * 256 + row * 8] = f2b(laiv);    // lai slot (k=24) for t+1
        if (s == 7) __builtin_nontemporal_store(laiv, outp + (size_t)t * 9 + 7);
      }
      if (s == 0) {                           // foi8 = o4[:,1] (reuses hx)
        float a8 = 0.f;
#pragma unroll
        for (int j = 0; j < 16; ++j) a8 += hx[j] * fcw[8][cp * 16 + j];
        a8 += __shfl_xor(a8, 1); a8 += __shfl_xor(a8, 2); a8 += __shfl_xor(a8, 4);
        if (cp == 0) __builtin_nontemporal_store(a8 + bfc8, outp + (size_t)t * 9 + 8);
      }
      if (s < 7) {                            // foi s from cell fc_c
        const unsigned short* hq = hbuf + fc_c * 4096 + (cp * 2) * 256 + row * 8;
        bf16x8 u0 = ldw(hq), u1 = ldw(hq + 256);
        float a = 0.f;
#pragma unroll
        for (int j = 0; j < 8; ++j) a += b2f((unsigned short)u0[j]) * fcw[s][cp * 16 + j];
#pragma unroll
        for (int j = 0; j < 8; ++j) a += b2f((unsigned short)u1[j]) * fcw[s][cp * 16 + 8 + j];
        a += __shfl_xor(a, 1); a += __shfl_xor(a, 2); a += __shfl_xor(a, 4);
        if (cp == 0) __builtin_nontemporal_store(a + fcb, outp + (size_t)t * 9 + s);
      }
    }
    __syncthreads();
  }

  // final hidden states (fp32 register carry)
#pragma unroll
  for (int c = 0; c < 4; ++c) {
    union { float f[2]; unsigned long long u; } cv;
    cv.f[0] = hreg[c][0]; cv.f[1] = hreg[c][1];
    __builtin_nontemporal_store(cv.u,
        (unsigned long long*)(p.hf[c] + (size_t)(b0 + row) * H_ + col0));
  }
}

// ---------------- launcher ----------------
extern "C" void kernel_launch(void* const* d_in, const int* in_sizes, int n_in,
                              void* d_out, int out_size, void* d_ws, size_t ws_size,
                              hipStream_t stream) {
  (void)in_sizes; (void)n_in; (void)d_ws; (void)ws_size; (void)out_size;
  const float* x    = (const float*)d_in[0];
  const float* wih1 = (const float*)d_in[1];
  const float* whh1 = (const float*)d_in[2];
  const float* wih2 = (const float*)d_in[7];
  const float* whh2 = (const float*)d_in[8];
  const float* wih3 = (const float*)d_in[13];
  const float* whh3 = (const float*)d_in[14];
  const float* wih4 = (const float*)d_in[19];
  const float* whh4 = (const float*)d_in[20];

  prep_weights<<<(ARENA_EL + 255) / 256, 256, 0, stream>>>(
      wih1, wih2, wih3, wih4, whh1, whh2, whh3, whh4);

  P p;
  p.x = x;
  for (int c = 0; c < 4; ++c) {
    p.bih[c] = (const float*)d_in[3 + 6 * c];
    p.bhh[c] = (const float*)d_in[4 + 6 * c];
    p.wfc[c] = (const float*)d_in[5 + 6 * c];
    p.bfc[c] = (const float*)d_in[6 + 6 * c];
  }
  float* out = (float*)d_out;
  p.out = out;
  const size_t HF_OFF = (size_t)B_ * T_ * 9;
  const size_t HT_OFF = HF_OFF + 4ull * B_ * H_;
  const size_t HT_SZ  = (size_t)B_ * T_ * H_;
  for (int c = 0; c < 4; ++c) {
    p.hf[c] = out + HF_OFF + (size_t)c * B_ * H_;
    p.hT[c] = out + HT_OFF + (size_t)c * HT_SZ;
  }

  (void)hipFuncSetAttribute(reinterpret_cast<const void*>(gru_main),
                            hipFuncAttributeMaxDynamicSharedMemorySize, (int)SMEMB);
  gru_main<<<NG * NS, 256, SMEMB, stream>>>(p);
}

// Round 10
// 12111.707 us; speedup vs baseline: 1.1072x; 1.1072x over previous
//
#include <hip/hip_runtime.h>
#include <hip/hip_bf16.h>

// ---------------- problem constants ----------------
#define B_   1024
#define T_   365
#define D_   24
#define H_   128

// g_ws: bf16 weights, fragment-major TILE order (26 tiles), replicated
// NREP times so every block streams a PRIVATE copy (kills same-address
// L2-bank serialization across lockstepped CUs; replicas live in L3).
//  t0: wih1p [k32 x 384rows] 24KB   t1: wih2p 24KB (k=24 -> lai col)
//  t2-4: whh1 r/z/n [16 kg][128 row][8 e] 32KB each; t5-7: whh2
//  t8-13: wih3 (ka r,z,n | kb r,z,n); t14-16: whh3
//  t17-22: wih4 (ka | kb); t23-25: whh4
#define WS_ELEMS 417792
#define NREP 64
#define TBQ(q) (24576 + ((q) - 2) * 16384)

typedef __attribute__((ext_vector_type(8))) short bf16x8;
typedef __attribute__((ext_vector_type(4))) float f32x4;

__device__ __align__(16) unsigned short g_ws[(size_t)NREP * WS_ELEMS];

#define MFMA(a, b, c) __builtin_amdgcn_mfma_f32_16x16x32_bf16((a), (b), (c), 0, 0, 0)

// counted-vmcnt phase sync: wait own tile loads, raw barrier (no full drain)
#define SYNC_V(N) do { \
  __builtin_amdgcn_sched_barrier(0); \
  asm volatile("s_waitcnt vmcnt(" #N ") lgkmcnt(0)" ::: "memory"); \
  __builtin_amdgcn_s_barrier(); \
  __builtin_amdgcn_sched_barrier(0); \
} while (0)

#define SYNC_NV() do { \
  __builtin_amdgcn_sched_barrier(0); \
  asm volatile("s_waitcnt lgkmcnt(0)" ::: "memory"); \
  __builtin_amdgcn_s_barrier(); \
  __builtin_amdgcn_sched_barrier(0); \
} while (0)

__device__ __forceinline__ bf16x8 ldw(const unsigned short* p) {
  return *(const bf16x8*)p;
}
__device__ __forceinline__ unsigned short f2b(float f) {
  union { __hip_bfloat16 h; unsigned short u; } cv;
  cv.h = __float2bfloat16(f);   // RNE
  return cv.u;
}
__device__ __forceinline__ float b2f(unsigned short u) {
  union { float f; unsigned int u32; } cv;
  cv.u32 = ((unsigned int)u) << 16;
  return cv.f;
}
__device__ __forceinline__ float sigmoidf_(float x) { return 1.f / (1.f + __expf(-x)); }
__device__ __forceinline__ float tanhf_(float x) {
  float e = __expf(2.f * x);
  return 1.f - 2.f / (e + 1.f);
}

// async DMA: wave wid copies NCH KB, linear; lane contributes 16B per instr
template <int NCH>
__device__ __forceinline__ void dma_tile(const unsigned short* gsrc, unsigned short* lbuf,
                                         int wid, int lane) {
  const char* g = (const char*)gsrc + wid * (NCH * 1024) + lane * 16;
  char* l = (char*)lbuf + wid * (NCH * 1024);
#pragma unroll
  for (int j = 0; j < NCH; ++j)
    __builtin_amdgcn_global_load_lds(
        (const __attribute__((address_space(1))) void*)(g + j * 1024),
        (__attribute__((address_space(3))) void*)(l + j * 1024), 16, 0, 0);
}

// 4-MFMA gate-tile accumulate
__device__ __forceinline__ f32x4 gtile(const unsigned short* buf, int woff,
                                       const bf16x8* a, f32x4 acc) {
#pragma unroll
  for (int kc = 0; kc < 4; ++kc)
    acc = MFMA(a[kc], *(const bf16x8*)(buf + woff + kc * 4096), acc);
  return acc;
}

// ---------------- prologue: fp32 -> fragment-major bf16 tiles (x NREP) ----------------
__global__ void prep_weights(const float* wih1, const float* wih2,
                             const float* whh1, const float* whh2,
                             const float* whh3, const float* whh4,
                             const float* wih3, const float* wih4) {
  int i = blockIdx.x * blockDim.x + threadIdx.x;
  if (i >= WS_ELEMS) return;
  float v = 0.f;
  if (i < 12288) {                 // t0: (kg*384 + row)*8 + e
    int kg = i / 3072, rem = i % 3072, r = rem >> 3, e = rem & 7, k = kg * 8 + e;
    v = (k < 24) ? wih1[r * 24 + k] : 0.f;
  } else if (i < 24576) {          // t1
    int j = i - 12288;
    int kg = j / 3072, rem = j % 3072, r = rem >> 3, e = rem & 7, k = kg * 8 + e;
    v = (k < 25) ? wih2[r * 25 + k] : 0.f;
  } else {                         // gate tiles: (kg*128 + row)*8 + e
    int j = i - 24576;
    int q = j / 16384, L = j % 16384;
    int kg = L >> 10, r = (L & 1023) >> 3, e = L & 7, k = kg * 8 + e;
    if (q < 3)       v = whh1[(q * 128 + r) * 128 + k];
    else if (q < 6)  v = whh2[((q - 3) * 128 + r) * 128 + k];
    else if (q < 12) { int q2 = q - 6;  v = wih3[((q2 % 3) * 128 + r) * 256 + (q2 / 3) * 128 + k]; }
    else if (q < 15) v = whh3[((q - 12) * 128 + r) * 128 + k];
    else if (q < 21) { int q4 = q - 15; v = wih4[((q4 % 3) * 128 + r) * 256 + (q4 / 3) * 128 + k]; }
    else             v = whh4[((q - 21) * 128 + r) * 128 + k];
  }
  unsigned short b = f2b(v);
#pragma unroll 4
  for (int rep = 0; rep < NREP; ++rep)
    g_ws[(size_t)rep * WS_ELEMS + i] = b;
}

// ---------------- params ----------------
struct GruParams {
  const float* x;
  const float* bih[4];
  const float* bhh[4];
  const float* wfc[4];
  const float* bfc[4];
  float* out;        // [B][T][9]
  float* hf[4];      // [B][128]
  float* hT[4];      // [B][T][128]
};

// dynamic LDS layout (bytes)
#define L_PB0   0u
#define L_PB1   32768u
#define L_PB2   65536u
#define L_PB3   98304u
#define L_HF    131072u    // ushort [4][16][16][8] = 16384
#define L_XF    147456u    // float [2][16][24] = 3072
#define L_LAI   150528u    // float [16] = 64
#define L_FCW   150592u    // float [9][128] = 4608
#define SMEMB   155200u

__global__ __launch_bounds__(512) void gru_main(GruParams p) {
  extern __shared__ __align__(16) unsigned char smem[];
  unsigned short* pb0 = (unsigned short*)(smem + L_PB0);
  unsigned short* pb1 = (unsigned short*)(smem + L_PB1);
  unsigned short* pb2 = (unsigned short*)(smem + L_PB2);
  unsigned short* pb3 = (unsigned short*)(smem + L_PB3);
  unsigned short* hfr = (unsigned short*)(smem + L_HF);
  float* xfb = (float*)(smem + L_XF);          // [2][16][24]
  float* lai_s = (float*)(smem + L_LAI);
  float (*fcw)[128] = (float (*)[128])(smem + L_FCW);

  const int tid  = threadIdx.x;
  const int lane = tid & 63;
  const int wid  = tid >> 6;       // 0..7
  const int nlo  = lane & 15;
  const int khi  = lane >> 4;      // 0..3
  const int nh   = wid * 16 + nlo;
  const int b0   = blockIdx.x * 16;
  const int wgoff = khi * 1024 + nh * 8;     // gate-tile fragment base (ushorts)
  const int xwoff = khi * 3072 + nh * 8;     // x-weight-tile fragment base

  // per-block private weight replica (address decorrelation)
  const unsigned short* gw = g_ws + (size_t)blockIdx.x * WS_ELEMS;

  // ---- prologue LDS fills ----
  for (int i = tid; i < 8192; i += 512) hfr[i] = 0;
  if (tid < 16) lai_s[tid] = 0.f;
  for (int i = tid; i < 9 * 128; i += 512) {
    int rw = i >> 7, k = i & 127;
    const float* src; int lr;
    if (rw == 0)      { src = p.wfc[0]; lr = 0; }
    else if (rw < 4)  { src = p.wfc[1]; lr = rw - 1; }
    else if (rw < 7)  { src = p.wfc[2]; lr = rw - 4; }
    else              { src = p.wfc[3]; lr = rw - 7; }
    fcw[rw][k] = src[lr * H_ + k];
  }

  float hreg[4][4];
#pragma unroll
  for (int c = 0; c < 4; ++c)
#pragma unroll
    for (int q = 0; q < 4; ++q) hreg[c][q] = 0.f;

  float brz[4][2], bin[4], bhn[4];
#pragma unroll
  for (int c = 0; c < 4; ++c) {
    brz[c][0] = p.bih[c][nh] + p.bhh[c][nh];
    brz[c][1] = p.bih[c][128 + nh] + p.bhh[c][128 + nh];
    bin[c]    = p.bih[c][256 + nh];
    bhn[c]    = p.bhh[c][256 + nh];
  }

  // x DMA: 96 chunks of 16B per step; wave w handles chunks w*12..w*12+11 (lanes 0..11)
  const int chunk = wid * 12 + (lane < 12 ? lane : 11);
  const int xrow = chunk / 6, xoff = (chunk % 6) * 16;
  const char* xsrc = (const char*)(p.x + (size_t)(b0 + xrow) * (T_ * D_)) + xoff;
  char* xd0 = (char*)xfb + chunk * 16;
  char* xd1 = (char*)xfb + 1536 + chunk * 16;

  // FC assignment: 144 threads = 16 rows x 9 outputs
  const bool fc_on = (tid < 144);
  const int foi = tid % 9;
  int frow = 0, fcell = 0;
  float fb = 0.f;
  if (fc_on) {
    frow = tid / 9;
    if (foi == 0)     { fcell = 0; fb = p.bfc[0][0]; }
    else if (foi < 4) { fcell = 1; fb = p.bfc[1][foi - 1]; }
    else if (foi < 7) { fcell = 2; fb = p.bfc[2][foi - 4]; }
    else              { fcell = 3; fb = p.bfc[3][foi - 7]; }
  }

  __syncthreads();
  // prime: t0->pb0, t1->pb1, t2->pb2, x(t=0)->xf[0]; full drain once
  dma_tile<3>(gw + 0, pb0, wid, lane);
  dma_tile<3>(gw + 12288, pb1, wid, lane);
  dma_tile<4>(gw + TBQ(2), pb2, wid, lane);
  if (lane < 12)
    __builtin_amdgcn_global_load_lds(
        (const __attribute__((address_space(1))) void*)xsrc,
        (__attribute__((address_space(3))) void*)xd0, 16, 0, 0);
  xsrc += D_ * 4;   // now points at t=1
  asm volatile("s_waitcnt vmcnt(0) lgkmcnt(0)" ::: "memory");
  __builtin_amdgcn_s_barrier();

  const f32x4 zf = {0.f, 0.f, 0.f, 0.f};

#define LDA4(dst, C) do { \
  const unsigned short* s_ = hfr + (C) * 2048; \
  _Pragma("unroll") \
  for (int kc_ = 0; kc_ < 4; ++kc_) \
    (dst)[kc_] = ldw(s_ + ((kc_ * 4 + khi) * 16 + nlo) * 8); \
} while (0)

#define FINISH(C, Rv, Zv, Iv, Hv) do { \
  unsigned short* hd_ = hfr + (C) * 2048; \
  _Pragma("unroll") \
  for (int q_ = 0; q_ < 4; ++q_) { \
    int m_ = khi * 4 + q_; \
    float r_ = sigmoidf_((Rv)[q_] + brz[C][0]); \
    float z_ = sigmoidf_((Zv)[q_] + brz[C][1]); \
    float n_ = tanhf_((Iv)[q_] + bin[C] + r_ * ((Hv)[q_] + bhn[C])); \
    float hn_ = (1.f - z_) * n_ + z_ * hreg[C][q_]; \
    hreg[C][q_] = hn_; \
    hd_[((nh >> 3) * 16 + m_) * 8 + (nh & 7)] = f2b(hn_); \
  } \
} while (0)

#define DMA4(q, dst) dma_tile<4>(gw + TBQ(q), (dst), wid, lane)

  for (int t = 0; t < T_; ++t) {
    const float* xf = xfb + (t & 1) * 384;   // [16][24] f32 for this step

    // P0 (t0=wih1p in pb0)
    SYNC_V(23);
    DMA4(3, pb3);
    bf16x8 ax;
    if (khi < 3) {
      const float* xp = xf + nlo * 24 + khi * 8;
      float4 lo = *(const float4*)xp;
      float4 hi = *(const float4*)(xp + 4);
      ax[0] = (short)f2b(lo.x); ax[1] = (short)f2b(lo.y);
      ax[2] = (short)f2b(lo.z); ax[3] = (short)f2b(lo.w);
      ax[4] = (short)f2b(hi.x); ax[5] = (short)f2b(hi.y);
      ax[6] = (short)f2b(hi.z); ax[7] = (short)f2b(hi.w);
    } else {
      ax = (bf16x8){0, 0, 0, 0, 0, 0, 0, 0};
      ax[0] = (short)f2b(lai_s[nlo]);
    }
    f32x4 R1 = MFMA(ax, ldw(pb0 + xwoff), zf);
    f32x4 Z1 = MFMA(ax, ldw(pb0 + xwoff + 1024), zf);
    f32x4 I1 = MFMA(ax, ldw(pb0 + xwoff + 2048), zf);
    // P1 (t1=wih2p in pb1)
    SYNC_V(24);
    DMA4(4, pb0);
    f32x4 R2 = MFMA(ax, ldw(pb1 + xwoff), zf);
    f32x4 Z2 = MFMA(ax, ldw(pb1 + xwoff + 1024), zf);
    f32x4 I2 = MFMA(ax, ldw(pb1 + xwoff + 2048), zf);
    // P2 (t2=whh1_r in pb2)
    SYNC_V(24);
    DMA4(5, pb1);
    bf16x8 a1[4]; LDA4(a1, 0);
    R1 = gtile(pb2, wgoff, a1, R1);
    // P3 (t3=whh1_z in pb3)
    SYNC_V(8);
    DMA4(6, pb2);
    Z1 = gtile(pb3, wgoff, a1, Z1);
    // P4 (t4=whh1_n in pb0) + x prefetch for t+1
    SYNC_V(8);
    DMA4(7, pb3);
    if (t + 1 < T_) {
      char* xd = ((t + 1) & 1) ? xd1 : xd0;
      if (lane < 12)
        __builtin_amdgcn_global_load_lds(
            (const __attribute__((address_space(1))) void*)xsrc,
            (__attribute__((address_space(3))) void*)xd, 16, 0, 0);
    }
    { f32x4 H1 = gtile(pb0, wgoff, a1, zf); FINISH(0, R1, Z1, I1, H1); }
    // P5 (t5=whh2_r in pb1)
    SYNC_V(9);
    DMA4(8, pb0);
    bf16x8 a2[4]; LDA4(a2, 1);
    R2 = gtile(pb1, wgoff, a2, R2);
    // P6 (t6=whh2_z in pb2)
    SYNC_V(9);
    DMA4(9, pb1);
    Z2 = gtile(pb2, wgoff, a2, Z2);
    // P7 (t7=whh2_n in pb3)
    SYNC_V(9);
    DMA4(10, pb2);
    { f32x4 H2 = gtile(pb3, wgoff, a2, zf); FINISH(1, R2, Z2, I2, H2); }
    // P8 (t8=w3_r_ka in pb0)
    SYNC_V(8);
    DMA4(11, pb3);
    bf16x8 h1n[4]; LDA4(h1n, 0);
    f32x4 R3 = gtile(pb0, wgoff, h1n, zf);
    // P9 (t9=w3_z_ka in pb1)
    SYNC_V(8);
    DMA4(12, pb0);
    f32x4 Z3 = gtile(pb1, wgoff, h1n, zf);
    // P10 (t10=w3_n_ka in pb2)
    SYNC_V(8);
    DMA4(13, pb1);
    f32x4 I3 = gtile(pb2, wgoff, h1n, zf);
    // P11 (t11=w3_r_kb in pb3)
    SYNC_V(8);
    DMA4(14, pb2);
    bf16x8 h2n[4]; LDA4(h2n, 1);
    R3 = gtile(pb3, wgoff, h2n, R3);
    // P12 (t12=w3_z_kb in pb0)
    SYNC_V(8);
    DMA4(15, pb3);
    Z3 = gtile(pb0, wgoff, h2n, Z3);
    // P13 (t13=w3_n_kb in pb1)
    SYNC_V(8);
    DMA4(16, pb0);
    I3 = gtile(pb1, wgoff, h2n, I3);
    // P14 (t14=whh3_r in pb2)
    SYNC_V(8);
    DMA4(17, pb1);
    bf16x8 a3[4]; LDA4(a3, 2);
    R3 = gtile(pb2, wgoff, a3, R3);
    // P15 (t15=whh3_z in pb3)
    SYNC_V(8);
    DMA4(18, pb2);
    Z3 = gtile(pb3, wgoff, a3, Z3);
    // P16 (t16=whh3_n in pb0)
    SYNC_V(8);
    DMA4(19, pb3);
    { f32x4 H3 = gtile(pb0, wgoff, a3, zf); FINISH(2, R3, Z3, I3, H3); }
    // P17 (t17=w4_r_ka in pb1)
    SYNC_V(8);
    DMA4(20, pb0);
    f32x4 R4 = gtile(pb1, wgoff, h1n, zf);
    // P18 (t18=w4_z_ka in pb2)
    SYNC_V(8);
    DMA4(21, pb1);
    f32x4 Z4 = gtile(pb2, wgoff, h1n, zf);
    // P19 (t19=w4_n_ka in pb3)
    SYNC_V(8);
    DMA4(22, pb2);
    f32x4 I4 = gtile(pb3, wgoff, h1n, zf);
    // P20 (t20=w4_r_kb in pb0)
    SYNC_V(8);
    DMA4(23, pb3);
    bf16x8 h3n[4]; LDA4(h3n, 2);
    R4 = gtile(pb0, wgoff, h3n, R4);
    // P21 (t21=w4_z_kb in pb1)
    SYNC_V(8);
    DMA4(24, pb0);
    Z4 = gtile(pb1, wgoff, h3n, Z4);
    // P22 (t22=w4_n_kb in pb2)
    SYNC_V(8);
    DMA4(25, pb1);
    I4 = gtile(pb2, wgoff, h3n, I4);
    // P23 (t23=whh4_r in pb3); issue next-step t0 -> pb2
    SYNC_V(8);
    dma_tile<3>(gw + 0, pb2, wid, lane);
    bf16x8 a4[4]; LDA4(a4, 3);
    R4 = gtile(pb3, wgoff, a4, R4);
    // P24 (t24=whh4_z in pb0); issue next-step t1 -> pb3
    SYNC_V(7);
    dma_tile<3>(gw + 12288, pb3, wid, lane);
    Z4 = gtile(pb0, wgoff, a4, Z4);
    // P25 (t25=whh4_n in pb1); issue next-step t2 -> pb0
    SYNC_V(6);
    DMA4(2, pb0);
    { f32x4 H4 = gtile(pb1, wgoff, a4, zf); FINISH(3, R4, Z4, I4, H4); }

    // ===== FC phase: hT stores + FC heads + lai =====
    SYNC_NV();
#pragma unroll
    for (int c = 0; c < 4; ++c)
#pragma unroll
      for (int q = 0; q < 4; ++q)
        p.hT[c][(size_t)(b0 + khi * 4 + q) * (T_ * H_) + (size_t)t * H_ + nh] = hreg[c][q];
    if (fc_on) {
      const unsigned short* hb = hfr + fcell * 2048 + frow * 8;
      float acc = fb;
#pragma unroll
      for (int kg = 0; kg < 16; ++kg) {
        bf16x8 hv = ldw(hb + kg * 128);
        float4 wA = *(const float4*)&fcw[foi][kg * 8];
        float4 wB = *(const float4*)&fcw[foi][kg * 8 + 4];
        acc += b2f((unsigned short)hv[0]) * wA.x + b2f((unsigned short)hv[1]) * wA.y +
               b2f((unsigned short)hv[2]) * wA.z + b2f((unsigned short)hv[3]) * wA.w +
               b2f((unsigned short)hv[4]) * wB.x + b2f((unsigned short)hv[5]) * wB.y +
               b2f((unsigned short)hv[6]) * wB.z + b2f((unsigned short)hv[7]) * wB.w;
      }
      p.out[(size_t)(b0 + frow) * (T_ * 9) + t * 9 + foi] = acc;
      if (foi == 7) lai_s[frow] = acc;   // o4 col 0 -> lai for next step
    }
    xsrc += D_ * 4;
    // rotate stream buffers: tile index advances 26 == 2 (mod 4)
    { unsigned short* tp;
      tp = pb0; pb0 = pb2; pb2 = tp;
      tp = pb1; pb1 = pb3; pb3 = tp; }
  }

  asm volatile("s_waitcnt vmcnt(0)" ::: "memory");   // retire dangling prefetches

  // final hidden states (fp32 register carry)
#pragma unroll
  for (int c = 0; c < 4; ++c)
#pragma unroll
    for (int q = 0; q < 4; ++q)
      p.hf[c][(size_t)(b0 + khi * 4 + q) * H_ + nh] = hreg[c][q];
}

// ---------------- launcher ----------------
extern "C" void kernel_launch(void* const* d_in, const int* in_sizes, int n_in,
                              void* d_out, int out_size, void* d_ws, size_t ws_size,
                              hipStream_t stream) {
  (void)in_sizes; (void)n_in; (void)d_ws; (void)ws_size; (void)out_size;
  const float* x    = (const float*)d_in[0];
  const float* wih1 = (const float*)d_in[1];
  const float* whh1 = (const float*)d_in[2];
  const float* wih2 = (const float*)d_in[7];
  const float* whh2 = (const float*)d_in[8];
  const float* wih3 = (const float*)d_in[13];
  const float* whh3 = (const float*)d_in[14];
  const float* wih4 = (const float*)d_in[19];
  const float* whh4 = (const float*)d_in[20];

  prep_weights<<<(WS_ELEMS + 255) / 256, 256, 0, stream>>>(wih1, wih2, whh1, whh2,
                                                           whh3, whh4, wih3, wih4);

  GruParams p;
  p.x = x;
  for (int c = 0; c < 4; ++c) {
    p.bih[c] = (const float*)d_in[3 + 6 * c];
    p.bhh[c] = (const float*)d_in[4 + 6 * c];
    p.wfc[c] = (const float*)d_in[5 + 6 * c];
    p.bfc[c] = (const float*)d_in[6 + 6 * c];
  }
  float* out = (float*)d_out;
  p.out = out;
  const size_t HF_OFF = (size_t)B_ * T_ * 9;
  const size_t HT_OFF = HF_OFF + 4ull * B_ * H_;
  const size_t HT_SZ  = (size_t)B_ * T_ * H_;
  for (int c = 0; c < 4; ++c) {
    p.hf[c] = out + HF_OFF + (size_t)c * B_ * H_;
    p.hT[c] = out + HT_OFF + (size_t)c * HT_SZ;
  }

  (void)hipFuncSetAttribute(reinterpret_cast<const void*>(gru_main),
                            hipFuncAttributeMaxDynamicSharedMemorySize, (int)SMEMB);
  gru_main<<<64, 512, SMEMB, stream>>>(p);
}

// Round 13
// 4356.634 us; speedup vs baseline: 3.0781x; 2.7801x over previous
//
#include <hip/hip_runtime.h>
#include <hip/hip_bf16.h>

// ---------------- problem constants ----------------
#define B_ 1024
#define T_ 365
#define D_ 24
#define H_ 128
#define NG 32            // batch groups (4 per XCD)
#define NS 8             // hidden slices (blocks per group, all on ONE XCD)
#define GB 32            // batch rows per group

// per-slice weight arena: 102 tiles x 512 ushorts ([khi4][nlo16][e8] frag layout)
#define SLICE_EL 52224
#define ARENA_EL (8 * SLICE_EL)

typedef __attribute__((ext_vector_type(8))) short bf16x8;
typedef __attribute__((ext_vector_type(4))) float f32x4;

__device__ __align__(16) unsigned short g_arena[ARENA_EL];
__device__ __align__(16) unsigned g_mb[4][NG][2048];  // [cell][group][kg16][row32][e4(pairs)]
__device__ unsigned g_flags[NG][4];
__device__ unsigned g_tick[8];                        // per-XCD ticket counters

#define MFMA(a, b, c) __builtin_amdgcn_mfma_f32_16x16x32_bf16((a), (b), (c), 0, 0, 0)

__device__ __forceinline__ bf16x8 ldw(const unsigned short* p) {
  return *(const bf16x8*)p;
}
__device__ __forceinline__ unsigned short f2b(float f) {
  union { __hip_bfloat16 h; unsigned short u; } cv;
  cv.h = __float2bfloat16(f);   // RNE
  return cv.u;
}
__device__ __forceinline__ float b2f(unsigned short u) {
  union { float f; unsigned int u32; } cv;
  cv.u32 = ((unsigned int)u) << 16;
  return cv.f;
}
__device__ __forceinline__ float sigmoidf_(float x) { return 1.f / (1.f + __expf(-x)); }
__device__ __forceinline__ float tanhf_(float x) {
  float e = __expf(2.f * x);
  return 1.f - 2.f / (e + 1.f);
}

// intra-XCD mailbox: producer sc0 store (write-through to shared L2),
// consumer sc0 load (L1-bypass, hits same L2). Flags go memory-side (sc01).
__device__ __forceinline__ void st_l2(unsigned* p, unsigned v) {
  asm volatile("global_store_dword %0, %1, off sc0" :: "v"(p), "v"(v) : "memory");
}
__device__ __forceinline__ unsigned ld_dev(const unsigned* p) {
  unsigned v;
  asm volatile("global_load_dword %0, %1, off sc0 sc1\n\ts_waitcnt vmcnt(0)"
               : "=v"(v) : "v"(p) : "memory");
  return v;
}

// ---------------- prologue: fp32 -> per-slice fragment-major bf16 arena ----------------
__global__ void prep_weights(const float* wih1, const float* wih2,
                             const float* wih3, const float* wih4,
                             const float* whh1, const float* whh2,
                             const float* whh3, const float* whh4) {
  int i = blockIdx.x * blockDim.x + threadIdx.x;
  if (i < NG * 4) ((unsigned*)g_flags)[i] = 0;   // zero sync flags each launch
  if (i < 8) g_tick[i] = 0;                      // zero XCD tickets each launch
  if (i >= ARENA_EL) return;
  int s = i / SLICE_EL, r = i % SLICE_EL;
  int tile = r >> 9, wi = r & 511;
  int khi = wi >> 7, nlo = (wi >> 3) & 15, e = wi & 7;
  float v = 0.f;
  if (tile < 3) {
    int row = tile * 128 + s * 16 + nlo, k = khi * 8 + e;
    if (k < 24) v = wih1[row * 24 + k];
  } else if (tile < 6) {
    int row = (tile - 3) * 128 + s * 16 + nlo, k = khi * 8 + e;
    if (k < 25) v = wih2[row * 25 + k];            // k=24 -> lai weight
  } else if (tile < 18) {
    int tt = tile - 6; int row = (tt >> 2) * 128 + s * 16 + nlo;
    v = whh1[row * 128 + (tt & 3) * 32 + khi * 8 + e];
  } else if (tile < 30) {
    int tt = tile - 18; int row = (tt >> 2) * 128 + s * 16 + nlo;
    v = whh2[row * 128 + (tt & 3) * 32 + khi * 8 + e];
  } else if (tile < 54) {
    int tt = tile - 30; int row = (tt >> 3) * 128 + s * 16 + nlo;
    v = wih3[row * 256 + (tt & 7) * 32 + khi * 8 + e];
  } else if (tile < 66) {
    int tt = tile - 54; int row = (tt >> 2) * 128 + s * 16 + nlo;
    v = whh3[row * 128 + (tt & 3) * 32 + khi * 8 + e];
  } else if (tile < 90) {
    int tt = tile - 66; int row = (tt >> 3) * 128 + s * 16 + nlo;
    v = wih4[row * 256 + (tt & 7) * 32 + khi * 8 + e];
  } else {
    int tt = tile - 90; int row = (tt >> 2) * 128 + s * 16 + nlo;
    v = whh4[row * 128 + (tt & 3) * 32 + khi * 8 + e];
  }
  g_arena[i] = f2b(v);
}

// ---------------- params ----------------
struct P {
  const float* x;
  const float* bih[4];
  const float* bhh[4];
  const float* wfc[4];
  const float* bfc[4];
  float* out;      // [B][T][9]
  float* hf[4];    // [B][128]
  float* hT[4];    // [B][T][128]
};

// group sync. CRITICAL: explicit vmcnt drain first — the mailbox stores are
// inline asm the compiler can't see, so __syncthreads alone won't drain them
// (this was the r11/r12 staleness bug).
__device__ __forceinline__ void gsync(int g, int st, unsigned target) {
  asm volatile("s_waitcnt vmcnt(0)" ::: "memory");
  __syncthreads();
  if (threadIdx.x == 0) {
    __hip_atomic_fetch_add(&g_flags[g][st], 1u, __ATOMIC_RELAXED, __HIP_MEMORY_SCOPE_AGENT);
    const unsigned* fp = &g_flags[g][st];
    unsigned v = ld_dev(fp);
    unsigned spins = 0;
    while (v < target && ++spins < (1u << 22)) {   // bounded: fails loudly, never hangs
      __builtin_amdgcn_s_sleep(2);
      v = ld_dev(fp);
    }
  }
  __syncthreads();
}

// dynamic LDS layout (bytes)
#define L_WSL  0u         // 102 KB weight slice
#define L_HBUF 104448u    // 4 cells x [16kg][32row][8e] ushort = 32768
#define L_PSUM 137216u    // [4 slot][2 mt][16 m][16 n] f32 = 8192
#define L_XA   145408u    // [4kg][32][8] ushort = 2048
#define L_FCW  147456u    // [9][128] f32 = 4608
#define SMEMB  152064u

__global__ __launch_bounds__(256, 1) void gru_main(P p) {
  extern __shared__ __align__(16) unsigned char smem[];
  unsigned short* wsl = (unsigned short*)(smem + L_WSL);
  unsigned short* hbuf = (unsigned short*)(smem + L_HBUF);
  float* psum = (float*)(smem + L_PSUM);
  unsigned short* xa = (unsigned short*)(smem + L_XA);
  float (*fcw)[H_] = (float (*)[H_])(smem + L_FCW);

  const int tid = threadIdx.x;
  const int lane = tid & 63;
  const int w = tid >> 6;            // wave role: 0=R 1=Z 2=In 3=Hn
  const int nlo = lane & 15, khi = lane >> 4;

  // ---- XCD-local group/slice assignment (ticket within physical XCD) ----
  // 256 blocks, 1 block/CU (152 KB LDS) -> exactly 32 blocks per XCD.
  int* meta = (int*)psum;   // psum unused until stages
  if (tid == 0) {
    unsigned xcc = __builtin_amdgcn_s_getreg((3 << 11) | 20) & 7;  // HW_REG_XCC_ID
    unsigned tk = __hip_atomic_fetch_add(&g_tick[xcc], 1u,
                                         __ATOMIC_RELAXED, __HIP_MEMORY_SCOPE_AGENT);
    tk &= 31;
    meta[0] = (int)(xcc * 4 + (tk >> 3));   // group: 4 per XCD
    meta[1] = (int)(tk & 7);                // slice within group
  }
  __syncthreads();
  const int g = meta[0], s = meta[1];
  __syncthreads();

  const int b0 = g * GB;
  const int wkoff = khi * 128 + nlo * 8;   // weight-frag offset (ushorts)
  const int hkoff = khi * 256 + nlo * 8;   // h/x-frag offset
  const int row = tid >> 3, cp = tid & 7;  // nonlin/FC ownership: 2 cols per thread
  const int col0 = s * 16 + cp * 2;
  const int mbw = (col0 >> 3) * 128 + row * 4 + ((col0 & 7) >> 1);  // word index

  // ---- prologue ----
  { const uint4* srcw = (const uint4*)(g_arena + s * SLICE_EL);
    uint4* dstw = (uint4*)wsl;
    for (int i = tid; i < SLICE_EL / 8; i += 256) dstw[i] = srcw[i]; }
  for (int i = tid; i < 8192; i += 256) ((unsigned*)hbuf)[i] = 0;
  for (int i = tid; i < 1024; i += 256) {       // xa for t=0 (lai=0, pad=0)
    int kg = i >> 8, rem = i & 255, r2 = rem >> 3, e = i & 7;
    int c = kg * 8 + e;
    unsigned short vv = 0;
    if (c < 24) vv = f2b(p.x[(size_t)(b0 + r2) * (T_ * D_) + c]);
    xa[i] = vv;
  }
  for (int i = tid; i < 9 * H_; i += 256) {
    int rw = i >> 7, k = i & 127;
    const float* srcf; int lr;
    if (rw == 0)      { srcf = p.wfc[0]; lr = 0; }
    else if (rw < 4)  { srcf = p.wfc[1]; lr = rw - 1; }
    else if (rw < 7)  { srcf = p.wfc[2]; lr = rw - 4; }
    else              { srcf = p.wfc[3]; lr = rw - 7; }
    fcw[rw][k] = srcf[lr * H_ + k];
  }

  float bR[4][2], bZ[4][2], bI[4][2], bHn[4][2], hreg[4][2];
#pragma unroll
  for (int c = 0; c < 4; ++c)
#pragma unroll
    for (int j = 0; j < 2; ++j) {
      int cc = col0 + j;
      bR[c][j]  = p.bih[c][cc] + p.bhh[c][cc];
      bZ[c][j]  = p.bih[c][H_ + cc] + p.bhh[c][H_ + cc];
      bI[c][j]  = p.bih[c][2 * H_ + cc];
      bHn[c][j] = p.bhh[c][2 * H_ + cc];
      hreg[c][j] = 0.f;
    }
  const float bfc7 = p.bfc[3][0];
  const float bfc8 = p.bfc[3][1];
  int fc_c = 0; float fcb = 0.f;
  if (s == 0)      { fc_c = 0; fcb = p.bfc[0][0]; }
  else if (s < 4)  { fc_c = 1; fcb = p.bfc[1][s - 1]; }
  else if (s < 7)  { fc_c = 2; fcb = p.bfc[2][s - 4]; }

  float* hTp[4];
#pragma unroll
  for (int c = 0; c < 4; ++c)
    hTp[c] = p.hT[c] + (size_t)(b0 + row) * (T_ * H_) + col0;
  float* outp = p.out + (size_t)(b0 + row) * (T_ * 9);

  const f32x4 zf = {0.f, 0.f, 0.f, 0.f};

#define WF(tt)        ldw(wsl + (tt) * 512 + wkoff)
#define HF(c, kc, mt) ldw(hbuf + (c) * 4096 + (kc) * 1024 + (mt) * 128 + hkoff)
#define XF(mt)        ldw(xa + (mt) * 128 + hkoff)
#define PWR(slot, mt, v) do { \
  float* pp_ = psum + (slot) * 512 + (mt) * 256 + khi * 64 + nlo; \
  pp_[0] = (v)[0]; pp_[16] = (v)[1]; pp_[32] = (v)[2]; pp_[48] = (v)[3]; \
} while (0)

#define STAGE_A(C, TWX, THX) do { \
  if (w < 2) { \
    _Pragma("unroll") \
    for (int mt = 0; mt < 2; ++mt) { \
      f32x4 acc = MFMA(XF(mt), WF((TWX) + w), zf); \
      _Pragma("unroll") \
      for (int kc = 0; kc < 4; ++kc) acc = MFMA(HF(C, kc, mt), WF((THX) + w * 4 + kc), acc); \
      PWR(w, mt, acc); \
    } \
  } else if (w == 2) { \
    _Pragma("unroll") \
    for (int mt = 0; mt < 2; ++mt) { f32x4 acc = MFMA(XF(mt), WF((TWX) + 2), zf); PWR(2, mt, acc); } \
  } else { \
    _Pragma("unroll") \
    for (int mt = 0; mt < 2; ++mt) { \
      f32x4 acc = zf; \
      _Pragma("unroll") \
      for (int kc = 0; kc < 4; ++kc) acc = MFMA(HF(C, kc, mt), WF((THX) + 8 + kc), acc); \
      PWR(3, mt, acc); \
    } \
  } \
} while (0)

#define STAGE_BC(CA, CB, CH, TWX, THX) do { \
  if (w < 2) { \
    _Pragma("unroll") \
    for (int mt = 0; mt < 2; ++mt) { \
      f32x4 acc = zf; \
      _Pragma("unroll") \
      for (int kc = 0; kc < 4; ++kc) acc = MFMA(HF(CA, kc, mt), WF((TWX) + w * 8 + kc), acc); \
      _Pragma("unroll") \
      for (int kc = 0; kc < 4; ++kc) acc = MFMA(HF(CB, kc, mt), WF((TWX) + w * 8 + 4 + kc), acc); \
      _Pragma("unroll") \
      for (int kc = 0; kc < 4; ++kc) acc = MFMA(HF(CH, kc, mt), WF((THX) + w * 4 + kc), acc); \
      PWR(w, mt, acc); \
    } \
  } else if (w == 2) { \
    _Pragma("unroll") \
    for (int mt = 0; mt < 2; ++mt) { \
      f32x4 acc = zf; \
      _Pragma("unroll") \
      for (int kc = 0; kc < 4; ++kc) acc = MFMA(HF(CA, kc, mt), WF((TWX) + 16 + kc), acc); \
      _Pragma("unroll") \
      for (int kc = 0; kc < 4; ++kc) acc = MFMA(HF(CB, kc, mt), WF((TWX) + 16 + 4 + kc), acc); \
      PWR(2, mt, acc); \
    } \
  } else { \
    _Pragma("unroll") \
    for (int mt = 0; mt < 2; ++mt) { \
      f32x4 acc = zf; \
      _Pragma("unroll") \
      for (int kc = 0; kc < 4; ++kc) acc = MFMA(HF(CH, kc, mt), WF((THX) + 8 + kc), acc); \
      PWR(3, mt, acc); \
    } \
  } \
} while (0)

#define FIN(C) do { \
  const float* pb_ = psum + (row >> 4) * 256 + (row & 15) * 16 + cp * 2; \
  float R0 = pb_[0],    Ra = pb_[1]; \
  float Z0 = pb_[512],  Za = pb_[513]; \
  float I0 = pb_[1024], Ia = pb_[1025]; \
  float G0 = pb_[1536], Ga = pb_[1537]; \
  float r0 = sigmoidf_(R0 + bR[C][0]), r1 = sigmoidf_(Ra + bR[C][1]); \
  float z0 = sigmoidf_(Z0 + bZ[C][0]), z1 = sigmoidf_(Za + bZ[C][1]); \
  float n0 = tanhf_(I0 + bI[C][0] + r0 * (G0 + bHn[C][0])); \
  float n1 = tanhf_(Ia + bI[C][1] + r1 * (Ga + bHn[C][1])); \
  float h0 = (1.f - z0) * n0 + z0 * hreg[C][0]; \
  float h1 = (1.f - z1) * n1 + z1 * hreg[C][1]; \
  hreg[C][0] = h0; hreg[C][1] = h1; \
  unsigned pk_ = (unsigned)f2b(h0) | ((unsigned)f2b(h1) << 16); \
  st_l2(&g_mb[C][g][0] + mbw, pk_); \
  union { float f[2]; unsigned long long u; } cv_; \
  cv_.f[0] = h0; cv_.f[1] = h1; \
  __builtin_nontemporal_store(cv_.u, (unsigned long long*)hTp[C]); \
  hTp[C] += H_; \
} while (0)

#define COPYMB(C) do { \
  const uint4* sm_ = (const uint4*)&g_mb[C][g][0]; \
  uint4 va_, vb_; \
  asm volatile("global_load_dwordx4 %0, %2, off sc0\n\t" \
               "global_load_dwordx4 %1, %3, off sc0\n\t" \
               "s_waitcnt vmcnt(0)" \
               : "=&v"(va_), "=&v"(vb_) \
               : "v"(sm_ + tid), "v"(sm_ + tid + 256) : "memory"); \
  uint4* dm_ = (uint4*)(hbuf + (C) * 4096); \
  dm_[tid] = va_; dm_[tid + 256] = vb_; \
} while (0)

  __syncthreads();

  for (int t = 0; t < T_; ++t) {
    // ===== stage A: cell1 =====
    STAGE_A(0, 0, 6);
    __syncthreads();
    FIN(0);
    __syncthreads();
    // ===== stage A: cell2 (xa col24 = lai) =====
    STAGE_A(1, 3, 18);
    __syncthreads();
    FIN(1);
    gsync(g, 0, 8u * (t + 1));

    // ===== stage B: cell3 =====
    COPYMB(0); COPYMB(1);       // h1,h2 new -> hbuf
    __syncthreads();
    STAGE_BC(0, 1, 2, 30, 54);
    __syncthreads();
    FIN(2);
    gsync(g, 1, 8u * (t + 1));

    // ===== stage C: cell4 =====
    COPYMB(2);                  // h3 new -> hbuf
    __syncthreads();
    STAGE_BC(0, 2, 3, 66, 90);
    __syncthreads();
    FIN(3);
    gsync(g, 2, 8u * (t + 1));

    // ===== FC phase =====
    COPYMB(3);                  // h4 new -> hbuf
    if (t + 1 < T_) {           // stage x_{t+1}
      for (int i = tid; i < GB * D_; i += 256) {
        int r2 = i / D_, cc = i % D_;
        xa[(cc >> 3) * 256 + r2 * 8 + (cc & 7)] =
            f2b(p.x[(size_t)(b0 + r2) * (T_ * D_) + (size_t)(t + 1) * D_ + cc]);
      }
    }
    __syncthreads();
    {
      // lai (all slices, redundant): o4[:,0] = h4 . wfc4[0] + b
      float hx[16];
      const unsigned short* hp = hbuf + 3 * 4096 + (cp * 2) * 256 + row * 8;
      bf16x8 v0 = ldw(hp), v1 = ldw(hp + 256);
#pragma unroll
      for (int e = 0; e < 8; ++e) {
        hx[e] = b2f((unsigned short)v0[e]);
        hx[8 + e] = b2f((unsigned short)v1[e]);
      }
      float acc = 0.f;
#pragma unroll
      for (int j = 0; j < 16; ++j) acc += hx[j] * fcw[7][cp * 16 + j];
      acc += __shfl_xor(acc, 1); acc += __shfl_xor(acc, 2); acc += __shfl_xor(acc, 4);
      float laiv = acc + bfc7;
      if (cp == 0) {
        xa[3 * 256 + row * 8] = f2b(laiv);    // lai slot (k=24) for t+1
        if (s == 7) __builtin_nontemporal_store(laiv, outp + (size_t)t * 9 + 7);
      }
      if (s == 0) {                           // foi8 = o4[:,1] (reuses hx)
        float a8 = 0.f;
#pragma unroll
        for (int j = 0; j < 16; ++j) a8 += hx[j] * fcw[8][cp * 16 + j];
        a8 += __shfl_xor(a8, 1); a8 += __shfl_xor(a8, 2); a8 += __shfl_xor(a8, 4);
        if (cp == 0) __builtin_nontemporal_store(a8 + bfc8, outp + (size_t)t * 9 + 8);
      }
      if (s < 7) {                            // foi s from cell fc_c
        const unsigned short* hq = hbuf + fc_c * 4096 + (cp * 2) * 256 + row * 8;
        bf16x8 u0 = ldw(hq), u1 = ldw(hq + 256);
        float a = 0.f;
#pragma unroll
        for (int j = 0; j < 8; ++j) a += b2f((unsigned short)u0[j]) * fcw[s][cp * 16 + j];
#pragma unroll
        for (int j = 0; j < 8; ++j) a += b2f((unsigned short)u1[j]) * fcw[s][cp * 16 + 8 + j];
        a += __shfl_xor(a, 1); a += __shfl_xor(a, 2); a += __shfl_xor(a, 4);
        if (cp == 0) __builtin_nontemporal_store(a + fcb, outp + (size_t)t * 9 + s);
      }
    }
    __syncthreads();
  }

  // final hidden states (fp32 register carry)
#pragma unroll
  for (int c = 0; c < 4; ++c) {
    union { float f[2]; unsigned long long u; } cv;
    cv.f[0] = hreg[c][0]; cv.f[1] = hreg[c][1];
    __builtin_nontemporal_store(cv.u,
        (unsigned long long*)(p.hf[c] + (size_t)(b0 + row) * H_ + col0));
  }
}

// ---------------- launcher ----------------
extern "C" void kernel_launch(void* const* d_in, const int* in_sizes, int n_in,
                              void* d_out, int out_size, void* d_ws, size_t ws_size,
                              hipStream_t stream) {
  (void)in_sizes; (void)n_in; (void)d_ws; (void)ws_size; (void)out_size;
  const float* x    = (const float*)d_in[0];
  const float* wih1 = (const float*)d_in[1];
  const float* whh1 = (const float*)d_in[2];
  const float* wih2 = (const float*)d_in[7];
  const float* whh2 = (const float*)d_in[8];
  const float* wih3 = (const float*)d_in[13];
  const float* whh3 = (const float*)d_in[14];
  const float* wih4 = (const float*)d_in[19];
  const float* whh4 = (const float*)d_in[20];

  prep_weights<<<(ARENA_EL + 255) / 256, 256, 0, stream>>>(
      wih1, wih2, wih3, wih4, whh1, whh2, whh3, whh4);

  P p;
  p.x = x;
  for (int c = 0; c < 4; ++c) {
    p.bih[c] = (const float*)d_in[3 + 6 * c];
    p.bhh[c] = (const float*)d_in[4 + 6 * c];
    p.wfc[c] = (const float*)d_in[5 + 6 * c];
    p.bfc[c] = (const float*)d_in[6 + 6 * c];
  }
  float* out = (float*)d_out;
  p.out = out;
  const size_t HF_OFF = (size_t)B_ * T_ * 9;
  const size_t HT_OFF = HF_OFF + 4ull * B_ * H_;
  const size_t HT_SZ  = (size_t)B_ * T_ * H_;
  for (int c = 0; c < 4; ++c) {
    p.hf[c] = out + HF_OFF + (size_t)c * B_ * H_;
    p.hT[c] = out + HT_OFF + (size_t)c * HT_SZ;
  }

  (void)hipFuncSetAttribute(reinterpret_cast<const void*>(gru_main),
                            hipFuncAttributeMaxDynamicSharedMemorySize, (int)SMEMB);
  gru_main<<<NG * NS, 256, SMEMB, stream>>>(p);
}

// Round 16
// 4189.157 us; speedup vs baseline: 3.2011x; 1.0400x over previous
//
#include <hip/hip_runtime.h>
#include <hip/hip_bf16.h>

// ---------------- problem constants ----------------
#define B_ 1024
#define T_ 365
#define D_ 24
#define H_ 128
#define NG 32            // batch groups (4 per XCD)
#define NS 8             // hidden slices (blocks per group, all on ONE XCD)
#define GB 32            // batch rows per group

// per-slice weight arena: 102 tiles x 512 ushorts ([khi4][nlo16][e8] frag layout)
#define SLICE_EL 52224
#define ARENA_EL (8 * SLICE_EL)

typedef __attribute__((ext_vector_type(8))) short bf16x8;
typedef __attribute__((ext_vector_type(4))) float f32x4;

__device__ __align__(16) unsigned short g_arena[ARENA_EL];
__device__ __align__(16) unsigned g_mb[4][NG][2048];  // [cell][group][kg16][row32][e4(pairs)]
__device__ unsigned g_flags[NG][4];
__device__ unsigned g_tick[8];                        // per-XCD ticket counters

#define MFMA(a, b, c) __builtin_amdgcn_mfma_f32_16x16x32_bf16((a), (b), (c), 0, 0, 0)

// LDS-only barrier (no vmcnt drain; guards psum/hbuf/xa phases only)
#define BAR() do { \
  __builtin_amdgcn_sched_barrier(0); \
  asm volatile("s_waitcnt lgkmcnt(0)" ::: "memory"); \
  __builtin_amdgcn_s_barrier(); \
  __builtin_amdgcn_sched_barrier(0); \
} while (0)

__device__ __forceinline__ bf16x8 ldw(const unsigned short* p) {
  return *(const bf16x8*)p;
}
__device__ __forceinline__ unsigned short f2b(float f) {
  union { __hip_bfloat16 h; unsigned short u; } cv;
  cv.h = __float2bfloat16(f);   // RNE
  return cv.u;
}
__device__ __forceinline__ float b2f(unsigned short u) {
  union { float f; unsigned int u32; } cv;
  cv.u32 = ((unsigned int)u) << 16;
  return cv.f;
}
__device__ __forceinline__ float sigmoidf_(float x) { return 1.f / (1.f + __expf(-x)); }
__device__ __forceinline__ float tanhf_(float x) {
  float e = __expf(2.f * x);
  return 1.f - 2.f / (e + 1.f);
}

// intra-XCD mailbox: producer sc0 store (write-through to shared L2),
// consumer sc0 load (L1-bypass, hits same L2). (r13-proven)
__device__ __forceinline__ void st_l2(unsigned* p, unsigned v) {
  asm volatile("global_store_dword %0, %1, off sc0" :: "v"(p), "v"(v) : "memory");
}
// device-coherent spin load (memory-side; r13-proven)
__device__ __forceinline__ unsigned ld_dev(const unsigned* p) {
  unsigned v;
  asm volatile("global_load_dword %0, %1, off sc0 sc1\n\ts_waitcnt vmcnt(0)"
               : "=v"(v) : "v"(p) : "memory");
  return v;
}

// ---------------- prologue: fp32 -> per-slice fragment-major bf16 arena ----------------
__global__ void prep_weights(const float* wih1, const float* wih2,
                             const float* wih3, const float* wih4,
                             const float* whh1, const float* whh2,
                             const float* whh3, const float* whh4) {
  int i = blockIdx.x * blockDim.x + threadIdx.x;
  if (i < NG * 4) ((unsigned*)g_flags)[i] = 0;   // zero sync flags each launch
  if (i < 8) g_tick[i] = 0;                      // zero XCD tickets each launch
  if (i >= ARENA_EL) return;
  int s = i / SLICE_EL, r = i % SLICE_EL;
  int tile = r >> 9, wi = r & 511;
  int khi = wi >> 7, nlo = (wi >> 3) & 15, e = wi & 7;
  float v = 0.f;
  if (tile < 3) {
    int row = tile * 128 + s * 16 + nlo, k = khi * 8 + e;
    if (k < 24) v = wih1[row * 24 + k];
  } else if (tile < 6) {
    int row = (tile - 3) * 128 + s * 16 + nlo, k = khi * 8 + e;
    if (k < 25) v = wih2[row * 25 + k];            // k=24 -> lai weight
  } else if (tile < 18) {
    int tt = tile - 6; int row = (tt >> 2) * 128 + s * 16 + nlo;
    v = whh1[row * 128 + (tt & 3) * 32 + khi * 8 + e];
  } else if (tile < 30) {
    int tt = tile - 18; int row = (tt >> 2) * 128 + s * 16 + nlo;
    v = whh2[row * 128 + (tt & 3) * 32 + khi * 8 + e];
  } else if (tile < 54) {
    int tt = tile - 30; int row = (tt >> 3) * 128 + s * 16 + nlo;
    v = wih3[row * 256 + (tt & 7) * 32 + khi * 8 + e];
  } else if (tile < 66) {
    int tt = tile - 54; int row = (tt >> 2) * 128 + s * 16 + nlo;
    v = whh3[row * 128 + (tt & 3) * 32 + khi * 8 + e];
  } else if (tile < 90) {
    int tt = tile - 66; int row = (tt >> 3) * 128 + s * 16 + nlo;
    v = wih4[row * 256 + (tt & 7) * 32 + khi * 8 + e];
  } else {
    int tt = tile - 90; int row = (tt >> 2) * 128 + s * 16 + nlo;
    v = whh4[row * 128 + (tt & 3) * 32 + khi * 8 + e];
  }
  g_arena[i] = f2b(v);
}

// ---------------- params ----------------
struct P {
  const float* x;
  const float* bih[4];
  const float* bhh[4];
  const float* wfc[4];
  const float* bfc[4];
  float* out;      // [B][T][9]
  float* hf[4];    // [B][128]
  float* hT[4];    // [B][T][128]
};

// group sync — EXACT r13 mechanism (proven): explicit vmcnt drain (asm mailbox
// stores are compiler-invisible), memory-side atomic flag, sc01 spin.
__device__ __forceinline__ void gsync(int g, int st, unsigned target) {
  asm volatile("s_waitcnt vmcnt(0)" ::: "memory");
  __syncthreads();
  if (threadIdx.x == 0) {
    __hip_atomic_fetch_add(&g_flags[g][st], 1u, __ATOMIC_RELAXED, __HIP_MEMORY_SCOPE_AGENT);
    const unsigned* fp = &g_flags[g][st];
    unsigned v = ld_dev(fp);
    unsigned spins = 0;
    while (v < target && ++spins < (1u << 22)) {   // bounded: fails loudly, never hangs
      v = ld_dev(fp);
    }
  }
  __syncthreads();
}

// dynamic LDS layout (bytes)
#define L_WSL  0u         // 102 KB weight slice
#define L_HBUF 104448u    // 4 cells x [16kg][32row][8e] ushort = 32768
#define L_PSUM 137216u    // [4 slot][2 mt][16 m][16 n] f32 = 8192
#define L_XA   145408u    // [4kg][32][8] ushort = 2048
#define L_FCW  147456u    // [9][128] f32 = 4608
#define SMEMB  152064u

__global__ __launch_bounds__(256, 1) void gru_main(P p) {
  extern __shared__ __align__(16) unsigned char smem[];
  unsigned short* wsl = (unsigned short*)(smem + L_WSL);
  unsigned short* hbuf = (unsigned short*)(smem + L_HBUF);
  float* psum = (float*)(smem + L_PSUM);
  unsigned short* xa = (unsigned short*)(smem + L_XA);
  float (*fcw)[H_] = (float (*)[H_])(smem + L_FCW);

  const int tid = threadIdx.x;
  const int lane = tid & 63;
  const int w = tid >> 6;            // wave role: 0=R 1=Z 2=In 3=Hn
  const int nlo = lane & 15, khi = lane >> 4;

  // ---- XCD-local group/slice assignment (ticket within physical XCD) ----
  int* meta = (int*)psum;   // psum unused until stages
  if (tid == 0) {
    unsigned xcc = __builtin_amdgcn_s_getreg((3 << 11) | 20) & 7;  // HW_REG_XCC_ID
    unsigned tk = __hip_atomic_fetch_add(&g_tick[xcc], 1u,
                                         __ATOMIC_RELAXED, __HIP_MEMORY_SCOPE_AGENT);
    tk &= 31;
    meta[0] = (int)(xcc * 4 + (tk >> 3));   // group: 4 per XCD
    meta[1] = (int)(tk & 7);                // slice within group
  }
  __syncthreads();
  const int g = meta[0], s = meta[1];
  __syncthreads();

  const int b0 = g * GB;
  const int wkoff = khi * 128 + nlo * 8;   // weight-frag offset (ushorts)
  const int hkoff = khi * 256 + nlo * 8;   // h/x-frag offset
  const int row = tid >> 3, cp = tid & 7;  // nonlin/FC ownership: 2 cols per thread
  const int col0 = s * 16 + cp * 2;
  const int mbw = (col0 >> 3) * 128 + row * 4 + ((col0 & 7) >> 1);  // word index

  // ---- prologue ----
  { const uint4* srcw = (const uint4*)(g_arena + s * SLICE_EL);
    uint4* dstw = (uint4*)wsl;
    for (int i = tid; i < SLICE_EL / 8; i += 256) dstw[i] = srcw[i]; }
  for (int i = tid; i < 8192; i += 256) ((unsigned*)hbuf)[i] = 0;
  for (int i = tid; i < 1024; i += 256) {       // xa for t=0 (lai=0, pad=0)
    int kg = i >> 8, rem = i & 255, r2 = rem >> 3, e = i & 7;
    int c = kg * 8 + e;
    unsigned short vv = 0;
    if (c < 24) vv = f2b(p.x[(size_t)(b0 + r2) * (T_ * D_) + c]);
    xa[i] = vv;
  }
  for (int i = tid; i < 9 * H_; i += 256) {
    int rw = i >> 7, k = i & 127;
    const float* srcf; int lr;
    if (rw == 0)      { srcf = p.wfc[0]; lr = 0; }
    else if (rw < 4)  { srcf = p.wfc[1]; lr = rw - 1; }
    else if (rw < 7)  { srcf = p.wfc[2]; lr = rw - 4; }
    else              { srcf = p.wfc[3]; lr = rw - 7; }
    fcw[rw][k] = srcf[lr * H_ + k];
  }

  float bR[4][2], bZ[4][2], bI[4][2], bHn[4][2], hreg[4][2];
#pragma unroll
  for (int c = 0; c < 4; ++c)
#pragma unroll
    for (int j = 0; j < 2; ++j) {
      int cc = col0 + j;
      bR[c][j]  = p.bih[c][cc] + p.bhh[c][cc];
      bZ[c][j]  = p.bih[c][H_ + cc] + p.bhh[c][H_ + cc];
      bI[c][j]  = p.bih[c][2 * H_ + cc];
      bHn[c][j] = p.bhh[c][2 * H_ + cc];
      hreg[c][j] = 0.f;
    }
  const float bfc7 = p.bfc[3][0];
  const float bfc8 = p.bfc[3][1];
  int fc_c = 0; float fcb = 0.f;
  if (s == 0)      { fc_c = 0; fcb = p.bfc[0][0]; }
  else if (s < 4)  { fc_c = 1; fcb = p.bfc[1][s - 1]; }
  else if (s < 7)  { fc_c = 2; fcb = p.bfc[2][s - 4]; }

  float* hTp[4];
#pragma unroll
  for (int c = 0; c < 4; ++c)
    hTp[c] = p.hT[c] + (size_t)(b0 + row) * (T_ * H_) + col0;
  float* outp = p.out + (size_t)(b0 + row) * (T_ * 9);

  const f32x4 zf = {0.f, 0.f, 0.f, 0.f};

#define WF(tt)        ldw(wsl + (tt) * 512 + wkoff)
#define HF(c, kc, mt) ldw(hbuf + (c) * 4096 + (kc) * 1024 + (mt) * 128 + hkoff)
#define XF(mt)        ldw(xa + (mt) * 128 + hkoff)
#define PWR(slot, mt, v) do { \
  float* pp_ = psum + (slot) * 512 + (mt) * 256 + khi * 64 + nlo; \
  pp_[0] = (v)[0]; pp_[16] = (v)[1]; pp_[32] = (v)[2]; pp_[48] = (v)[3]; \
} while (0)

#define STAGE_A(C, TWX, THX) do { \
  if (w < 2) { \
    _Pragma("unroll") \
    for (int mt = 0; mt < 2; ++mt) { \
      f32x4 acc = MFMA(XF(mt), WF((TWX) + w), zf); \
      _Pragma("unroll") \
      for (int kc = 0; kc < 4; ++kc) acc = MFMA(HF(C, kc, mt), WF((THX) + w * 4 + kc), acc); \
      PWR(w, mt, acc); \
    } \
  } else if (w == 2) { \
    _Pragma("unroll") \
    for (int mt = 0; mt < 2; ++mt) { f32x4 acc = MFMA(XF(mt), WF((TWX) + 2), zf); PWR(2, mt, acc); } \
  } else { \
    _Pragma("unroll") \
    for (int mt = 0; mt < 2; ++mt) { \
      f32x4 acc = zf; \
      _Pragma("unroll") \
      for (int kc = 0; kc < 4; ++kc) acc = MFMA(HF(C, kc, mt), WF((THX) + 8 + kc), acc); \
      PWR(3, mt, acc); \
    } \
  } \
} while (0)

#define STAGE_BC(CA, CB, CH, TWX, THX) do { \
  if (w < 2) { \
    _Pragma("unroll") \
    for (int mt = 0; mt < 2; ++mt) { \
      f32x4 acc = zf; \
      _Pragma("unroll") \
      for (int kc = 0; kc < 4; ++kc) acc = MFMA(HF(CA, kc, mt), WF((TWX) + w * 8 + kc), acc); \
      _Pragma("unroll") \
      for (int kc = 0; kc < 4; ++kc) acc = MFMA(HF(CB, kc, mt), WF((TWX) + w * 8 + 4 + kc), acc); \
      _Pragma("unroll") \
      for (int kc = 0; kc < 4; ++kc) acc = MFMA(HF(CH, kc, mt), WF((THX) + w * 4 + kc), acc); \
      PWR(w, mt, acc); \
    } \
  } else if (w == 2) { \
    _Pragma("unroll") \
    for (int mt = 0; mt < 2; ++mt) { \
      f32x4 acc = zf; \
      _Pragma("unroll") \
      for (int kc = 0; kc < 4; ++kc) acc = MFMA(HF(CA, kc, mt), WF((TWX) + 16 + kc), acc); \
      _Pragma("unroll") \
      for (int kc = 0; kc < 4; ++kc) acc = MFMA(HF(CB, kc, mt), WF((TWX) + 16 + 4 + kc), acc); \
      PWR(2, mt, acc); \
    } \
  } else { \
    _Pragma("unroll") \
    for (int mt = 0; mt < 2; ++mt) { \
      f32x4 acc = zf; \
      _Pragma("unroll") \
      for (int kc = 0; kc < 4; ++kc) acc = MFMA(HF(CH, kc, mt), WF((THX) + 8 + kc), acc); \
      PWR(3, mt, acc); \
    } \
  } \
} while (0)

// FIN: gates + h update + mailbox store ONLY (hT stores deferred to FC phase)
#define FIN(C) do { \
  const float* pb_ = psum + (row >> 4) * 256 + (row & 15) * 16 + cp * 2; \
  float R0 = pb_[0],    Ra = pb_[1]; \
  float Z0 = pb_[512],  Za = pb_[513]; \
  float I0 = pb_[1024], Ia = pb_[1025]; \
  float G0 = pb_[1536], Ga = pb_[1537]; \
  float r0 = sigmoidf_(R0 + bR[C][0]), r1 = sigmoidf_(Ra + bR[C][1]); \
  float z0 = sigmoidf_(Z0 + bZ[C][0]), z1 = sigmoidf_(Za + bZ[C][1]); \
  float n0 = tanhf_(I0 + bI[C][0] + r0 * (G0 + bHn[C][0])); \
  float n1 = tanhf_(Ia + bI[C][1] + r1 * (Ga + bHn[C][1])); \
  float h0 = (1.f - z0) * n0 + z0 * hreg[C][0]; \
  float h1 = (1.f - z1) * n1 + z1 * hreg[C][1]; \
  hreg[C][0] = h0; hreg[C][1] = h1; \
  unsigned pk_ = (unsigned)f2b(h0) | ((unsigned)f2b(h1) << 16); \
  st_l2(&g_mb[C][g][0] + mbw, pk_); \
} while (0)

#define COPYMB(C) do { \
  const uint4* sm_ = (const uint4*)&g_mb[C][g][0]; \
  uint4 va_, vb_; \
  asm volatile("global_load_dwordx4 %0, %2, off sc0\n\t" \
               "global_load_dwordx4 %1, %3, off sc0\n\t" \
               "s_waitcnt vmcnt(0)" \
               : "=&v"(va_), "=&v"(vb_) \
               : "v"(sm_ + tid), "v"(sm_ + tid + 256) : "memory"); \
  uint4* dm_ = (uint4*)(hbuf + (C) * 4096); \
  dm_[tid] = va_; dm_[tid + 256] = vb_; \
} while (0)

  __syncthreads();

  for (int t = 0; t < T_; ++t) {
    // ===== stage A: cell1 =====
    STAGE_A(0, 0, 6);
    BAR();
    FIN(0);
    BAR();
    // ===== stage A: cell2 (xa col24 = lai) =====
    STAGE_A(1, 3, 18);
    BAR();
    FIN(1);
    gsync(g, 0, 8u * (t + 1));

    // ===== stage B: cell3 =====
    COPYMB(0); COPYMB(1);       // h1,h2 new -> hbuf
    BAR();
    STAGE_BC(0, 1, 2, 30, 54);
    BAR();
    FIN(2);
    gsync(g, 1, 8u * (t + 1));

    // ===== stage C: cell4 =====
    COPYMB(2);                  // h3 new -> hbuf
    BAR();
    STAGE_BC(0, 2, 3, 66, 90);
    BAR();
    FIN(3);
    gsync(g, 2, 8u * (t + 1));

    // ===== FC phase =====
    COPYMB(3);                  // h4 new -> hbuf
    if (t + 1 < T_) {           // stage x_{t+1}
      for (int i = tid; i < GB * D_; i += 256) {
        int r2 = i / D_, cc = i % D_;
        xa[(cc >> 3) * 256 + r2 * 8 + (cc & 7)] =
            f2b(p.x[(size_t)(b0 + r2) * (T_ * D_) + (size_t)(t + 1) * D_ + cc]);
      }
    }
    // deferred hT stores (asm nt, compiler-invisible -> drain only at next gsync)
#pragma unroll
    for (int c = 0; c < 4; ++c) {
      union { float f[2]; unsigned long long u; } cv;
      cv.f[0] = hreg[c][0]; cv.f[1] = hreg[c][1];
      asm volatile("global_store_dwordx2 %0, %1, off nt"
                   :: "v"(hTp[c]), "v"(cv.u) : "memory");
      hTp[c] += H_;
    }
    BAR();
    {
      // lai (all slices, redundant): o4[:,0] = h4 . wfc4[0] + b
      float hx[16];
      const unsigned short* hp = hbuf + 3 * 4096 + (cp * 2) * 256 + row * 8;
      bf16x8 v0 = ldw(hp), v1 = ldw(hp + 256);
#pragma unroll
      for (int e = 0; e < 8; ++e) {
        hx[e] = b2f((unsigned short)v0[e]);
        hx[8 + e] = b2f((unsigned short)v1[e]);
      }
      float acc = 0.f;
#pragma unroll
      for (int j = 0; j < 16; ++j) acc += hx[j] * fcw[7][cp * 16 + j];
      acc += __shfl_xor(acc, 1); acc += __shfl_xor(acc, 2); acc += __shfl_xor(acc, 4);
      float laiv = acc + bfc7;
      if (cp == 0) {
        xa[3 * 256 + row * 8] = f2b(laiv);    // lai slot (k=24) for t+1
        if (s == 7) {
          float* op_ = outp + (size_t)t * 9 + 7;
          asm volatile("global_store_dword %0, %1, off nt" :: "v"(op_), "v"(laiv) : "memory");
        }
      }
      if (s == 0) {                           // foi8 = o4[:,1] (reuses hx)
        float a8 = 0.f;
#pragma unroll
        for (int j = 0; j < 16; ++j) a8 += hx[j] * fcw[8][cp * 16 + j];
        a8 += __shfl_xor(a8, 1); a8 += __shfl_xor(a8, 2); a8 += __shfl_xor(a8, 4);
        if (cp == 0) {
          float v8 = a8 + bfc8;
          float* op_ = outp + (size_t)t * 9 + 8;
          asm volatile("global_store_dword %0, %1, off nt" :: "v"(op_), "v"(v8) : "memory");
        }
      }
      if (s < 7) {                            // foi s from cell fc_c
        const unsigned short* hq = hbuf + fc_c * 4096 + (cp * 2) * 256 + row * 8;
        bf16x8 u0 = ldw(hq), u1 = ldw(hq + 256);
        float a = 0.f;
#pragma unroll
        for (int j = 0; j < 8; ++j) a += b2f((unsigned short)u0[j]) * fcw[s][cp * 16 + j];
#pragma unroll
        for (int j = 0; j < 8; ++j) a += b2f((unsigned short)u1[j]) * fcw[s][cp * 16 + 8 + j];
        a += __shfl_xor(a, 1); a += __shfl_xor(a, 2); a += __shfl_xor(a, 4);
        if (cp == 0) {
          float vs = a + fcb;
          float* op_ = outp + (size_t)t * 9 + s;
          asm volatile("global_store_dword %0, %1, off nt" :: "v"(op_), "v"(vs) : "memory");
        }
      }
    }
    BAR();
  }

  // final hidden states (fp32 register carry)
#pragma unroll
  for (int c = 0; c < 4; ++c) {
    union { float f[2]; unsigned long long u; } cv;
    cv.f[0] = hreg[c][0]; cv.f[1] = hreg[c][1];
    asm volatile("global_store_dwordx2 %0, %1, off nt"
                 :: "v"(p.hf[c] + (size_t)(b0 + row) * H_ + col0), "v"(cv.u) : "memory");
  }
  asm volatile("s_waitcnt vmcnt(0)" ::: "memory");   // retire all untracked stores
}

// ---------------- launcher ----------------
extern "C" void kernel_launch(void* const* d_in, const int* in_sizes, int n_in,
                              void* d_out, int out_size, void* d_ws, size_t ws_size,
                              hipStream_t stream) {
  (void)in_sizes; (void)n_in; (void)d_ws; (void)ws_size; (void)out_size;
  const float* x    = (const float*)d_in[0];
  const float* wih1 = (const float*)d_in[1];
  const float* whh1 = (const float*)d_in[2];
  const float* wih2 = (const float*)d_in[7];
  const float* whh2 = (const float*)d_in[8];
  const float* wih3 = (const float*)d_in[13];
  const float* whh3 = (const float*)d_in[14];
  const float* wih4 = (const float*)d_in[19];
  const float* whh4 = (const float*)d_in[20];

  prep_weights<<<(ARENA_EL + 255) / 256, 256, 0, stream>>>(
      wih1, wih2, wih3, wih4, whh1, whh2, whh3, whh4);

  P p;
  p.x = x;
  for (int c = 0; c < 4; ++c) {
    p.bih[c] = (const float*)d_in[3 + 6 * c];
    p.bhh[c] = (const float*)d_in[4 + 6 * c];
    p.wfc[c] = (const float*)d_in[5 + 6 * c];
    p.bfc[c] = (const float*)d_in[6 + 6 * c];
  }
  float* out = (float*)d_out;
  p.out = out;
  const size_t HF_OFF = (size_t)B_ * T_ * 9;
  const size_t HT_OFF = HF_OFF + 4ull * B_ * H_;
  const size_t HT_SZ  = (size_t)B_ * T_ * H_;
  for (int c = 0; c < 4; ++c) {
    p.hf[c] = out + HF_OFF + (size_t)c * B_ * H_;
    p.hT[c] = out + HT_OFF + (size_t)c * HT_SZ;
  }

  (void)hipFuncSetAttribute(reinterpret_cast<const void*>(gru_main),
                            hipFuncAttributeMaxDynamicSharedMemorySize, (int)SMEMB);
  gru_main<<<NG * NS, 256, SMEMB, stream>>>(p);
}